// Round 1
// 1491.805 us; speedup vs baseline: 1.0381x; 1.0381x over previous
//
#include <hip/hip_runtime.h>
#include <hip/hip_bf16.h>
#include <math.h>

#define NG 4096

typedef short bfrag __attribute__((ext_vector_type(8)));
typedef float f32x4 __attribute__((ext_vector_type(4)));

__device__ inline ushort f2bf(float v) {
  union { float f; unsigned u; } a; a.f = v;
  unsigned r = a.u + 0x7fffu + ((a.u >> 16) & 1u);
  return (ushort)(r >> 16);
}
__device__ inline float bf2f(ushort h) {
  union { unsigned u; float f; } a; a.u = ((unsigned)h) << 16;
  return a.f;
}

// ---------------- dtype detector: batch_indices int32 (stride 1) or int64 (stride 2)?
__global__ void detect_kernel(const int* __restrict__ idx32, int* __restrict__ flag) {
  __shared__ int s;
  int t = threadIdx.x;
  if (t == 0) s = 0;
  __syncthreads();
  int dec = 0;
  for (int i = t; i < 4095; i += 256)
    if (idx32[i + 1] < idx32[i]) dec = 1;
  if (dec) atomicOr(&s, 1);
  __syncthreads();
  if (t == 0) *flag = s ? 2 : 1;
}

// ---------------- segment starts from sorted indices
__global__ void bounds_kernel(const int* __restrict__ idx32, const int* __restrict__ flag,
                              int* __restrict__ starts, int n) {
  int st = *flag;
  int i = blockIdx.x * blockDim.x + threadIdx.x;
  if (i >= n) return;
  int cur = idx32[(size_t)i * st];
  int prev = (i == 0) ? -1 : idx32[(size_t)(i - 1) * st];
  if (cur != prev)
    for (int g = prev + 1; g <= cur; ++g) starts[g] = i;
  if (i == n - 1)
    for (int g = cur + 1; g <= NG; ++g) starts[g] = n;
}

// ---------------- weight prep.
// Wcat rows are PERMUTED so that in the gates GEMM each wave's four 16-col tiles
// (nt=0..3) hold gates i,f,g,o of the SAME hidden unit:
//   dest row n:  u = (n>>7)*32 + ((n>>6)&1)*16 + (n&15), q = (n>>4)&3,
//   source row ro = q*256 + u;  Wcat = W_ih + [W_hh | 0].
// All weights stored as split bf16 (hi + lo residual).
__global__ void wprep_kernel(const float* __restrict__ W_ih, const float* __restrict__ W_hh,
                             const float* __restrict__ b_ih, const float* __restrict__ b_hh,
                             const float* __restrict__ W1, const float* __restrict__ W2,
                             ushort* __restrict__ Wch, ushort* __restrict__ Wcl,
                             ushort* __restrict__ W1h, ushort* __restrict__ W1l,
                             ushort* __restrict__ W2h, ushort* __restrict__ W2l,
                             float* __restrict__ bcat) {
  int i = blockIdx.x * 256 + threadIdx.x;
  if (i < 524288) {
    int n = i >> 9, k = i & 511;
    int u = ((n >> 7) << 5) | (((n >> 6) & 1) << 4) | (n & 15);
    int q = (n >> 4) & 3;
    int ro = q * 256 + u;
    float w = W_ih[(size_t)ro * 512 + k] + (k < 256 ? W_hh[(size_t)ro * 256 + k] : 0.f);
    ushort hi = f2bf(w);
    Wch[i] = hi; Wcl[i] = f2bf(w - bf2f(hi));
    if (k == 0) bcat[n] = b_ih[ro] + b_hh[ro];
  } else if (i < 524288 + 131072) {
    int t = i - 524288;
    float w = W1[t];
    ushort hi = f2bf(w);
    W1h[t] = hi; W1l[t] = f2bf(w - bf2f(hi));
  } else if (i < 524288 + 131072 + 65536) {
    int t = i - 524288 - 131072;
    float w = W2[t];
    ushort hi = f2bf(w);
    W2h[t] = hi; W2l[t] = f2bf(w - bf2f(hi));
  }
}

// ---------------- step 0: h=0 => softmax exactly uniform => r = segment mean.
// Also zeroes c and the h ping-pong buffer 0 (h-half of x).
__global__ __launch_bounds__(256) void attn0_kernel(const float* __restrict__ emb,
                                                    const int* __restrict__ starts,
                                                    float* __restrict__ cst,
                                                    ushort* __restrict__ hbh, ushort* __restrict__ hbl,
                                                    ushort* __restrict__ rbh, ushort* __restrict__ rbl) {
  int g = blockIdx.x, tid = threadIdx.x;
  cst[(size_t)g * 256 + tid] = 0.f;
  hbh[(size_t)g * 256 + tid] = 0;
  hbl[(size_t)g * 256 + tid] = 0;
  int s = starts[g], e = starts[g + 1];
  if (s >= e) {
    rbh[(size_t)g * 256 + tid] = 0;
    rbl[(size_t)g * 256 + tid] = 0;
    return;
  }
  int wave = tid >> 6, lane = tid & 63;
  float4 R0 = make_float4(0.f, 0.f, 0.f, 0.f), R1 = make_float4(0.f, 0.f, 0.f, 0.f);
  for (int n = s + wave * 2; n < e; n += 8) {
    const float* p0 = emb + (size_t)n * 256 + lane * 4;
    float4 v0 = *(const float4*)p0;
    R0.x += v0.x; R0.y += v0.y; R0.z += v0.z; R0.w += v0.w;
    if (n + 1 < e) {
      float4 v1 = *(const float4*)(p0 + 256);
      R1.x += v1.x; R1.y += v1.y; R1.z += v1.z; R1.w += v1.w;
    }
  }
  R0.x += R1.x; R0.y += R1.y; R0.z += R1.z; R0.w += R1.w;
  __shared__ float redR[4][256];
  *(float4*)&redR[wave][lane * 4] = R0;
  __syncthreads();
  float inv = 1.f / (float)(e - s);
  float Rt = 0.f;
#pragma unroll
  for (int w = 0; w < 4; ++w) Rt += redR[w][tid];
  float rv = Rt * inv;
  ushort hi = f2bf(rv);
  rbh[(size_t)g * 256 + tid] = hi;
  rbl[(size_t)g * 256 + tid] = f2bf(rv - bf2f(hi));
}

// ---------------- fused attention (steps 1..5): h read from split-bf16 ping-pong buffer.
__global__ __launch_bounds__(256) void attn_kernel(const float* __restrict__ emb,
                                                   const int* __restrict__ starts,
                                                   const ushort* __restrict__ hbh,
                                                   const ushort* __restrict__ hbl,
                                                   ushort* __restrict__ rbh,
                                                   ushort* __restrict__ rbl) {
  int g = blockIdx.x;
  int s = starts[g], e = starts[g + 1];
  int tid = threadIdx.x;
  if (s >= e) {
    rbh[(size_t)g * 256 + tid] = 0;
    rbl[(size_t)g * 256 + tid] = 0;
    return;
  }
  __shared__ float hs[256];
  __shared__ float redM[4], redS[4];
  __shared__ float redR[4][256];
  hs[tid] = bf2f(hbh[(size_t)g * 256 + tid]) + bf2f(hbl[(size_t)g * 256 + tid]);
  __syncthreads();
  int wave = tid >> 6, lane = tid & 63;
  float4 h4 = *(const float4*)&hs[lane * 4];
  float M0 = -INFINITY, S0 = 0.f, M1 = -INFINITY, S1 = 0.f;
  float4 R0 = make_float4(0.f, 0.f, 0.f, 0.f), R1 = make_float4(0.f, 0.f, 0.f, 0.f);
  for (int n = s + wave * 2; n < e; n += 8) {
    const float* p0 = emb + (size_t)n * 256 + lane * 4;
    float4 v0 = *(const float4*)p0;
    bool has1 = (n + 1) < e;
    float4 v1 = make_float4(0.f, 0.f, 0.f, 0.f);
    if (has1) v1 = *(const float4*)(p0 + 256);
    float d0 = v0.x * h4.x + v0.y * h4.y + v0.z * h4.z + v0.w * h4.w;
    float d1 = v1.x * h4.x + v1.y * h4.y + v1.z * h4.z + v1.w * h4.w;
#pragma unroll
    for (int off = 32; off > 0; off >>= 1) {
      d0 += __shfl_xor(d0, off, 64);
      d1 += __shfl_xor(d1, off, 64);
    }
    if (d0 <= M0) {
      float w = __expf(d0 - M0);
      S0 += w;
      R0.x += w * v0.x; R0.y += w * v0.y; R0.z += w * v0.z; R0.w += w * v0.w;
    } else {
      float cc = __expf(M0 - d0);
      S0 = S0 * cc + 1.f;
      R0.x = R0.x * cc + v0.x; R0.y = R0.y * cc + v0.y;
      R0.z = R0.z * cc + v0.z; R0.w = R0.w * cc + v0.w;
      M0 = d0;
    }
    if (has1) {
      if (d1 <= M1) {
        float w = __expf(d1 - M1);
        S1 += w;
        R1.x += w * v1.x; R1.y += w * v1.y; R1.z += w * v1.z; R1.w += w * v1.w;
      } else {
        float cc = __expf(M1 - d1);
        S1 = S1 * cc + 1.f;
        R1.x = R1.x * cc + v1.x; R1.y = R1.y * cc + v1.y;
        R1.z = R1.z * cc + v1.z; R1.w = R1.w * cc + v1.w;
        M1 = d1;
      }
    }
  }
  if (M1 != -INFINITY) {  // merge chain1 into chain0
    float mm = fmaxf(M0, M1);
    float f0 = __expf(M0 - mm), f1 = __expf(M1 - mm);
    S0 = S0 * f0 + S1 * f1;
    R0.x = R0.x * f0 + R1.x * f1; R0.y = R0.y * f0 + R1.y * f1;
    R0.z = R0.z * f0 + R1.z * f1; R0.w = R0.w * f0 + R1.w * f1;
    M0 = mm;
  }
  if (lane == 0) { redM[wave] = M0; redS[wave] = S0; }
  *(float4*)&redR[wave][lane * 4] = R0;
  __syncthreads();
  float m = fmaxf(fmaxf(redM[0], redM[1]), fmaxf(redM[2], redM[3]));
  float St = 0.f, Rt = 0.f;
#pragma unroll
  for (int w = 0; w < 4; ++w) {
    float mw = redM[w];
    float f = (mw == -INFINITY) ? 0.f : __expf(mw - m);
    St += f * redS[w];
    Rt += f * redR[w][tid];
  }
  float rv = Rt / St;
  ushort hi = f2bf(rv);
  rbh[(size_t)g * 256 + tid] = hi;
  rbl[(size_t)g * 256 + tid] = f2bf(rv - bf2f(hi));
}

// ---------------- split-bf16 MFMA GEMM, register-prefetch pipelined.
// A = [A1 | A2] two split-bf16 buffers of row stride 256 (A2 used for k >= 256).
// mode 0: fp32 + bias store; mode 2: relu + split-bf16 store;
// mode 3: gate-interleaved LSTM epilogue (i,f,g,o per lane in registers) ->
//         writes c state and split-bf16 h into ping-pong buffer. No gates round-trip.
#define AP 40  // LDS row pitch in shorts (80B stride -> 2-way banks = free)
__global__ __launch_bounds__(256) void gemm_mfma(
    const ushort* __restrict__ Ah1, const ushort* __restrict__ Al1,
    const ushort* __restrict__ Ah2, const ushort* __restrict__ Al2,
    const ushort* __restrict__ Bhi, const ushort* __restrict__ Blo,
    const float* __restrict__ bias, float* __restrict__ Cf,
    ushort* __restrict__ Chi, ushort* __restrict__ Clo,
    float* __restrict__ cst, ushort* __restrict__ hoh, ushort* __restrict__ hol,
    int N, int K, int mode) {
  __shared__ ushort sAh[128 * AP], sAl[128 * AP], sBh[128 * AP], sBl[128 * AP];
  const int As = 256;
  int tid = threadIdx.x;
  int wave = tid >> 6, lane = tid & 63;
  int fr = lane & 15, fq = lane >> 4;
  int wm = (wave >> 1) * 64, wn = (wave & 1) * 64;
  int r0 = blockIdx.y * 128, c0 = blockIdx.x * 128;
  int lr = tid >> 2, lk = (tid & 3) * 8;
  const ushort* pbh = Bhi + (size_t)(c0 + lr) * K + lk;
  const ushort* pbl = Blo + (size_t)(c0 + lr) * K + lk;
  size_t rstrB = (size_t)64 * K;
  size_t rowA0 = (size_t)(r0 + lr) * As + lk;
  size_t rowA1 = (size_t)(r0 + lr + 64) * As + lk;
  int lo0 = lr * AP + lk, lo1 = (lr + 64) * AP + lk;
  uint4 a0, a1, a2, a3, b0, b1, b2, b3;
#define LOADT(kt) do { \
    const ushort *qh, *ql; int kk; \
    if ((kt) < As) { qh = Ah1; ql = Al1; kk = (kt); } \
    else { qh = Ah2; ql = Al2; kk = (kt) - As; } \
    a0 = *(const uint4*)(qh + rowA0 + kk); \
    a1 = *(const uint4*)(qh + rowA1 + kk); \
    a2 = *(const uint4*)(ql + rowA0 + kk); \
    a3 = *(const uint4*)(ql + rowA1 + kk); \
    b0 = *(const uint4*)(pbh + (kt)); \
    b1 = *(const uint4*)(pbh + rstrB + (kt)); \
    b2 = *(const uint4*)(pbl + (kt)); \
    b3 = *(const uint4*)(pbl + rstrB + (kt)); \
  } while (0)
#define STORET() do { \
    *(uint4*)&sAh[lo0] = a0; *(uint4*)&sAh[lo1] = a1; \
    *(uint4*)&sAl[lo0] = a2; *(uint4*)&sAl[lo1] = a3; \
    *(uint4*)&sBh[lo0] = b0; *(uint4*)&sBh[lo1] = b1; \
    *(uint4*)&sBl[lo0] = b2; *(uint4*)&sBl[lo1] = b3; \
  } while (0)
  LOADT(0);
  STORET();
  f32x4 acc[4][4] = {};
  for (int k0 = 0; k0 < K; k0 += 32) {
    __syncthreads();            // current tile visible in LDS
    bool nx = (k0 + 32) < K;
    if (nx) LOADT(k0 + 32);     // issue next tile loads; latency hides under MFMA
    bfrag ah[4], al[4], bh[4], bl[4];
#pragma unroll
    for (int t = 0; t < 4; ++t) {
      int ra = (wm + t * 16 + fr) * AP + fq * 8;
      int rb = (wn + t * 16 + fr) * AP + fq * 8;
      ah[t] = *(const bfrag*)&sAh[ra];
      al[t] = *(const bfrag*)&sAl[ra];
      bh[t] = *(const bfrag*)&sBh[rb];
      bl[t] = *(const bfrag*)&sBl[rb];
    }
#pragma unroll
    for (int mt = 0; mt < 4; ++mt)
#pragma unroll
      for (int nt = 0; nt < 4; ++nt) {
        acc[mt][nt] = __builtin_amdgcn_mfma_f32_16x16x32_bf16(ah[mt], bh[nt], acc[mt][nt], 0, 0, 0);
        acc[mt][nt] = __builtin_amdgcn_mfma_f32_16x16x32_bf16(ah[mt], bl[nt], acc[mt][nt], 0, 0, 0);
        acc[mt][nt] = __builtin_amdgcn_mfma_f32_16x16x32_bf16(al[mt], bh[nt], acc[mt][nt], 0, 0, 0);
      }
    __syncthreads();            // all frag reads done before LDS overwrite
    if (nx) STORET();
  }
#undef LOADT
#undef STORET
  if (mode == 3) {
    // gate-interleaved epilogue: nt = gate q (i,f,g,o), unit u fixed per lane.
    float bv0 = bias[c0 + wn + fr];
    float bv1 = bias[c0 + wn + 16 + fr];
    float bv2 = bias[c0 + wn + 32 + fr];
    float bv3 = bias[c0 + wn + 48 + fr];
    int u = (c0 >> 2) + (wn >> 2) + fr;
#pragma unroll
    for (int mt = 0; mt < 4; ++mt)
#pragma unroll
      for (int rg = 0; rg < 4; ++rg) {
        int m = r0 + wm + mt * 16 + fq * 4 + rg;
        float gi = acc[mt][0][rg] + bv0;
        float gf = acc[mt][1][rg] + bv1;
        float gg = acc[mt][2][rg] + bv2;
        float go = acc[mt][3][rg] + bv3;
        float si = 1.f / (1.f + __expf(-gi));
        float sf = 1.f / (1.f + __expf(-gf));
        float so = 1.f / (1.f + __expf(-go));
        float tg = tanhf(gg);
        size_t ci = (size_t)m * 256 + u;
        float cn = sf * cst[ci] + si * tg;
        cst[ci] = cn;
        float hn = so * tanhf(cn);
        ushort hi = f2bf(hn);
        hoh[ci] = hi;
        hol[ci] = f2bf(hn - bf2f(hi));
      }
    return;
  }
#pragma unroll
  for (int mt = 0; mt < 4; ++mt)
#pragma unroll
    for (int nt = 0; nt < 4; ++nt) {
      int n = c0 + wn + nt * 16 + fr;
      float bv = bias[n];
#pragma unroll
      for (int rg = 0; rg < 4; ++rg) {
        int m = r0 + wm + mt * 16 + fq * 4 + rg;
        float v = acc[mt][nt][rg] + bv;
        if (mode == 2) {
          v = fmaxf(v, 0.f);
          ushort hi = f2bf(v);
          Chi[(size_t)m * N + n] = hi;
          Clo[(size_t)m * N + n] = f2bf(v - bf2f(hi));
        } else {
          Cf[(size_t)m * N + n] = v;
        }
      }
    }
}

extern "C" void kernel_launch(void* const* d_in, const int* in_sizes, int n_in,
                              void* d_out, int out_size, void* d_ws, size_t ws_size,
                              hipStream_t stream) {
  const float* emb   = (const float*)d_in[0];
  const int*   idx32 = (const int*)d_in[1];
  const float* W_ih  = (const float*)d_in[2];
  const float* W_hh  = (const float*)d_in[3];
  const float* b_ih  = (const float*)d_in[4];
  const float* b_hh  = (const float*)d_in[5];
  const float* W1    = (const float*)d_in[6];
  const float* b1    = (const float*)d_in[7];
  const float* W2    = (const float*)d_in[8];
  const float* b2    = (const float*)d_in[9];
  float* out = (float*)d_out;
  int N = in_sizes[1];

  char* ws = (char*)d_ws;
  size_t o = 0;
  auto alloc = [&](size_t bytes) { void* p = ws + o; o = (o + bytes + 255) & ~(size_t)255; return p; };
  int*    flag  = (int*)alloc(4);
  int*    starts= (int*)alloc(((size_t)NG + 1) * 4);
  float*  bcat  = (float*)alloc(1024 * 4);
  ushort* Wch   = (ushort*)alloc((size_t)1024 * 512 * 2);
  ushort* Wcl   = (ushort*)alloc((size_t)1024 * 512 * 2);
  ushort* W1h   = (ushort*)alloc((size_t)256 * 512 * 2);
  ushort* W1l   = (ushort*)alloc((size_t)256 * 512 * 2);
  ushort* W2h   = (ushort*)alloc((size_t)256 * 256 * 2);
  ushort* W2l   = (ushort*)alloc((size_t)256 * 256 * 2);
  float*  c     = (float*)alloc((size_t)NG * 256 * 4);
  ushort* hbh0  = (ushort*)alloc((size_t)NG * 256 * 2);
  ushort* hbl0  = (ushort*)alloc((size_t)NG * 256 * 2);
  ushort* hbh1  = (ushort*)alloc((size_t)NG * 256 * 2);
  ushort* hbl1  = (ushort*)alloc((size_t)NG * 256 * 2);
  ushort* rbh   = (ushort*)alloc((size_t)NG * 256 * 2);
  ushort* rbl   = (ushort*)alloc((size_t)NG * 256 * 2);
  ushort* hdnh  = (ushort*)alloc((size_t)NG * 256 * 2);
  ushort* hdnl  = (ushort*)alloc((size_t)NG * 256 * 2);

  detect_kernel<<<1, 256, 0, stream>>>(idx32, flag);
  bounds_kernel<<<(N + 255) / 256, 256, 0, stream>>>(idx32, flag, starts, N);
  wprep_kernel<<<(524288 + 131072 + 65536) / 256, 256, 0, stream>>>(
      W_ih, W_hh, b_ih, b_hh, W1, W2, Wch, Wcl, W1h, W1l, W2h, W2l, bcat);
  attn0_kernel<<<NG, 256, 0, stream>>>(emb, starts, c, hbh0, hbl0, rbh, rbl);

  for (int s = 0; s < 6; ++s) {
    const ushort* hch = (s & 1) ? hbh1 : hbh0;
    const ushort* hcl = (s & 1) ? hbl1 : hbl0;
    ushort* hnh = (s & 1) ? hbh0 : hbh1;
    ushort* hnl = (s & 1) ? hbl0 : hbl1;
    gemm_mfma<<<dim3(1024 / 128, 4096 / 128), 256, 0, stream>>>(
        hch, hcl, rbh, rbl, Wch, Wcl, bcat,
        (float*)nullptr, (ushort*)nullptr, (ushort*)nullptr,
        c, hnh, hnl, 1024, 512, 3);
    if (s < 5)
      attn_kernel<<<NG, 256, 0, stream>>>(emb, starts, hnh, hnl, rbh, rbl);
  }
  // after s=5: h6 lives in hb0 (cur was hb1), r5 in rb
  gemm_mfma<<<dim3(256 / 128, 4096 / 128), 256, 0, stream>>>(
      hbh0, hbl0, rbh, rbl, W1h, W1l, b1,
      (float*)nullptr, hdnh, hdnl,
      (float*)nullptr, (ushort*)nullptr, (ushort*)nullptr, 256, 512, 2);
  gemm_mfma<<<dim3(256 / 128, 4096 / 128), 256, 0, stream>>>(
      hdnh, hdnl, hdnh, hdnl, W2h, W2l, b2,
      out, (ushort*)nullptr, (ushort*)nullptr,
      (float*)nullptr, (ushort*)nullptr, (ushort*)nullptr, 256, 256, 0);
}

// Round 2
// 1201.365 us; speedup vs baseline: 1.2891x; 1.2418x over previous
//
#include <hip/hip_runtime.h>
#include <hip/hip_bf16.h>
#include <hip/hip_fp16.h>
#include <math.h>

#define NG 4096

typedef short bfrag __attribute__((ext_vector_type(8)));
typedef float f32x4 __attribute__((ext_vector_type(4)));

__device__ inline ushort f2bf(float v) {
  union { float f; unsigned u; } a; a.f = v;
  unsigned r = a.u + 0x7fffu + ((a.u >> 16) & 1u);
  return (ushort)(r >> 16);
}
__device__ inline float bf2f(ushort h) {
  union { unsigned u; float f; } a; a.u = ((unsigned)h) << 16;
  return a.f;
}

// ---------------- dtype detector: batch_indices int32 (stride 1) or int64 (stride 2)?
__global__ void detect_kernel(const int* __restrict__ idx32, int* __restrict__ flag) {
  __shared__ int s;
  int t = threadIdx.x;
  if (t == 0) s = 0;
  __syncthreads();
  int dec = 0;
  for (int i = t; i < 4095; i += 256)
    if (idx32[i + 1] < idx32[i]) dec = 1;
  if (dec) atomicOr(&s, 1);
  __syncthreads();
  if (t == 0) *flag = s ? 2 : 1;
}

// ---------------- segment starts from sorted indices
__global__ void bounds_kernel(const int* __restrict__ idx32, const int* __restrict__ flag,
                              int* __restrict__ starts, int n) {
  int st = *flag;
  int i = blockIdx.x * blockDim.x + threadIdx.x;
  if (i >= n) return;
  int cur = idx32[(size_t)i * st];
  int prev = (i == 0) ? -1 : idx32[(size_t)(i - 1) * st];
  if (cur != prev)
    for (int g = prev + 1; g <= cur; ++g) starts[g] = i;
  if (i == n - 1)
    for (int g = cur + 1; g <= NG; ++g) starts[g] = n;
}

// ---------------- weight prep (gate-interleaved Wcat rows; split bf16 everywhere)
__global__ void wprep_kernel(const float* __restrict__ W_ih, const float* __restrict__ W_hh,
                             const float* __restrict__ b_ih, const float* __restrict__ b_hh,
                             const float* __restrict__ W1, const float* __restrict__ W2,
                             ushort* __restrict__ Wch, ushort* __restrict__ Wcl,
                             ushort* __restrict__ W1h, ushort* __restrict__ W1l,
                             ushort* __restrict__ W2h, ushort* __restrict__ W2l,
                             float* __restrict__ bcat) {
  int i = blockIdx.x * 256 + threadIdx.x;
  if (i < 524288) {
    int n = i >> 9, k = i & 511;
    int u = ((n >> 7) << 5) | (((n >> 6) & 1) << 4) | (n & 15);
    int q = (n >> 4) & 3;
    int ro = q * 256 + u;
    float w = W_ih[(size_t)ro * 512 + k] + (k < 256 ? W_hh[(size_t)ro * 256 + k] : 0.f);
    ushort hi = f2bf(w);
    Wch[i] = hi; Wcl[i] = f2bf(w - bf2f(hi));
    if (k == 0) bcat[n] = b_ih[ro] + b_hh[ro];
  } else if (i < 524288 + 131072) {
    int t = i - 524288;
    float w = W1[t];
    ushort hi = f2bf(w);
    W1h[t] = hi; W1l[t] = f2bf(w - bf2f(hi));
  } else if (i < 524288 + 131072 + 65536) {
    int t = i - 524288 - 131072;
    float w = W2[t];
    ushort hi = f2bf(w);
    W2h[t] = hi; W2l[t] = f2bf(w - bf2f(hi));
  }
}

// ---------------- step 0: h=0 => softmax uniform => r = segment mean.
// Side effect: writes fp16 shadow copy of emb (full coverage: every node is in a graph).
// Also zeroes c and h ping-pong buffer 0.
__global__ __launch_bounds__(256) void attn0_kernel(const float* __restrict__ emb,
                                                    const int* __restrict__ starts,
                                                    ushort* __restrict__ e16,
                                                    float* __restrict__ cst,
                                                    ushort* __restrict__ hbh, ushort* __restrict__ hbl,
                                                    ushort* __restrict__ rbh, ushort* __restrict__ rbl) {
  int g = blockIdx.x, tid = threadIdx.x;
  cst[(size_t)g * 256 + tid] = 0.f;
  hbh[(size_t)g * 256 + tid] = 0;
  hbl[(size_t)g * 256 + tid] = 0;
  int s = starts[g], e = starts[g + 1];
  if (s >= e) {
    rbh[(size_t)g * 256 + tid] = 0;
    rbl[(size_t)g * 256 + tid] = 0;
    return;
  }
  int wave = tid >> 6, lane = tid & 63;
  float4 R0 = make_float4(0.f, 0.f, 0.f, 0.f), R1 = make_float4(0.f, 0.f, 0.f, 0.f);
  for (int n = s + wave * 2; n < e; n += 8) {
    const float* p0 = emb + (size_t)n * 256 + lane * 4;
    float4 v0 = *(const float4*)p0;
    union { uint2 u; __half h[4]; } pk0;
    pk0.h[0] = __float2half_rn(v0.x); pk0.h[1] = __float2half_rn(v0.y);
    pk0.h[2] = __float2half_rn(v0.z); pk0.h[3] = __float2half_rn(v0.w);
    *(uint2*)(e16 + (size_t)n * 256 + lane * 4) = pk0.u;
    R0.x += v0.x; R0.y += v0.y; R0.z += v0.z; R0.w += v0.w;
    if (n + 1 < e) {
      float4 v1 = *(const float4*)(p0 + 256);
      union { uint2 u; __half h[4]; } pk1;
      pk1.h[0] = __float2half_rn(v1.x); pk1.h[1] = __float2half_rn(v1.y);
      pk1.h[2] = __float2half_rn(v1.z); pk1.h[3] = __float2half_rn(v1.w);
      *(uint2*)(e16 + (size_t)(n + 1) * 256 + lane * 4) = pk1.u;
      R1.x += v1.x; R1.y += v1.y; R1.z += v1.z; R1.w += v1.w;
    }
  }
  R0.x += R1.x; R0.y += R1.y; R0.z += R1.z; R0.w += R1.w;
  __shared__ float redR[4][256];
  *(float4*)&redR[wave][lane * 4] = R0;
  __syncthreads();
  float inv = 1.f / (float)(e - s);
  float Rt = 0.f;
#pragma unroll
  for (int w = 0; w < 4; ++w) Rt += redR[w][tid];
  float rv = Rt * inv;
  ushort hi = f2bf(rv);
  rbh[(size_t)g * 256 + tid] = hi;
  rbl[(size_t)g * 256 + tid] = f2bf(rv - bf2f(hi));
}

// ---------------- fused attention steps 1..5: fp16 emb, 2 rows per wave-load,
// one online-softmax chain per half-wave (8 chains/block), LDS merge.
__global__ __launch_bounds__(256) void attn_kernel(const ushort* __restrict__ e16,
                                                   const int* __restrict__ starts,
                                                   const ushort* __restrict__ hbh,
                                                   const ushort* __restrict__ hbl,
                                                   ushort* __restrict__ rbh,
                                                   ushort* __restrict__ rbl) {
  int g = blockIdx.x;
  int s = starts[g], e = starts[g + 1];
  int tid = threadIdx.x;
  if (s >= e) {
    rbh[(size_t)g * 256 + tid] = 0;
    rbl[(size_t)g * 256 + tid] = 0;
    return;
  }
  __shared__ float hs[256];
  __shared__ float redM[8], redS[8];
  __shared__ float redR[8][256];
  hs[tid] = bf2f(hbh[(size_t)g * 256 + tid]) + bf2f(hbl[(size_t)g * 256 + tid]);
  __syncthreads();
  int wave = tid >> 6, lane = tid & 63;
  int half = lane >> 5, l5 = lane & 31;
  float h8[8];
#pragma unroll
  for (int j = 0; j < 8; ++j) h8[j] = hs[l5 * 8 + j];
  float M = -1e30f, S = 0.f;
  float R[8] = {0.f, 0.f, 0.f, 0.f, 0.f, 0.f, 0.f, 0.f};
  for (int n = s + wave * 2; n < e; n += 8) {
    int row = n + half;
    int rowc = row < e ? row : (e - 1);
    union { uint4 u; __half h[8]; } uv;
    uv.u = *(const uint4*)(e16 + (size_t)rowc * 256 + l5 * 8);
    float vf[8];
    float d = 0.f;
#pragma unroll
    for (int j = 0; j < 8; ++j) {
      vf[j] = __half2float(uv.h[j]);
      d = fmaf(vf[j], h8[j], d);
    }
#pragma unroll
    for (int off = 16; off > 0; off >>= 1) d += __shfl_xor(d, off, 64);
    if (row >= e) d = -INFINITY;        // exp(-INF - M) == 0, M stays
    if (d <= M) {
      float w = __expf(d - M);
      S += w;
#pragma unroll
      for (int j = 0; j < 8; ++j) R[j] = fmaf(w, vf[j], R[j]);
    } else {
      float cc = __expf(M - d);         // M=-1e30 first time -> cc==0
      S = S * cc + 1.f;
#pragma unroll
      for (int j = 0; j < 8; ++j) R[j] = fmaf(R[j], cc, vf[j]);
      M = d;
    }
  }
  int ch = wave * 2 + half;
  if (l5 == 0) { redM[ch] = M; redS[ch] = S; }
#pragma unroll
  for (int j = 0; j < 8; ++j) redR[ch][l5 * 8 + j] = R[j];
  __syncthreads();
  float m = -1e30f;
#pragma unroll
  for (int w = 0; w < 8; ++w) m = fmaxf(m, redM[w]);
  float St = 0.f, Rt = 0.f;
#pragma unroll
  for (int w = 0; w < 8; ++w) {
    float f = __expf(redM[w] - m);      // empty chain: exp(-1e30 - m) == 0
    St += f * redS[w];
    Rt += f * redR[w][tid];
  }
  float rv = Rt / St;
  ushort hi = f2bf(rv);
  rbh[(size_t)g * 256 + tid] = hi;
  rbl[(size_t)g * 256 + tid] = f2bf(rv - bf2f(hi));
}

// ---------------- split-bf16 MFMA GEMM, 64x128 tile (2 blocks/CU on gates GEMM),
// register-prefetch pipelined. A = [A1 | A2] split-bf16, row stride 256.
// mode 0: fp32+bias; mode 2: relu + split-bf16; mode 3: fused LSTM epilogue.
#define AP 40  // LDS row pitch in shorts (80B stride -> 2-way banks = free)
__global__ __launch_bounds__(256) void gemm_mfma(
    const ushort* __restrict__ Ah1, const ushort* __restrict__ Al1,
    const ushort* __restrict__ Ah2, const ushort* __restrict__ Al2,
    const ushort* __restrict__ Bhi, const ushort* __restrict__ Blo,
    const float* __restrict__ bias, float* __restrict__ Cf,
    ushort* __restrict__ Chi, ushort* __restrict__ Clo,
    float* __restrict__ cst, ushort* __restrict__ hoh, ushort* __restrict__ hol,
    int N, int K, int mode) {
  __shared__ ushort sAh[64 * AP], sAl[64 * AP], sBh[128 * AP], sBl[128 * AP];
  const int As = 256;
  int tid = threadIdx.x;
  int wave = tid >> 6, lane = tid & 63;
  int fr = lane & 15, fq = lane >> 4;
  int wm = (wave >> 1) * 32, wn = (wave & 1) * 64;   // 2x2 waves, each 32x64
  int r0 = blockIdx.y * 64, c0 = blockIdx.x * 128;
  int lr = tid >> 2, lk = (tid & 3) * 8;
  const ushort* pbh = Bhi + (size_t)(c0 + lr) * K + lk;
  const ushort* pbl = Blo + (size_t)(c0 + lr) * K + lk;
  size_t rstrB = (size_t)64 * K;
  size_t rowA = (size_t)(r0 + lr) * As + lk;
  int lo0 = lr * AP + lk, lo1 = (lr + 64) * AP + lk;
  uint4 a0, a2, b0, b1, b2, b3;
#define LOADT(kt) do { \
    const ushort *qh, *ql; int kk; \
    if ((kt) < As) { qh = Ah1; ql = Al1; kk = (kt); } \
    else { qh = Ah2; ql = Al2; kk = (kt) - As; } \
    a0 = *(const uint4*)(qh + rowA + kk); \
    a2 = *(const uint4*)(ql + rowA + kk); \
    b0 = *(const uint4*)(pbh + (kt)); \
    b1 = *(const uint4*)(pbh + rstrB + (kt)); \
    b2 = *(const uint4*)(pbl + (kt)); \
    b3 = *(const uint4*)(pbl + rstrB + (kt)); \
  } while (0)
#define STORET() do { \
    *(uint4*)&sAh[lo0] = a0; *(uint4*)&sAl[lo0] = a2; \
    *(uint4*)&sBh[lo0] = b0; *(uint4*)&sBh[lo1] = b1; \
    *(uint4*)&sBl[lo0] = b2; *(uint4*)&sBl[lo1] = b3; \
  } while (0)
  LOADT(0);
  STORET();
  f32x4 acc[2][4] = {};
  for (int k0 = 0; k0 < K; k0 += 32) {
    __syncthreads();
    bool nx = (k0 + 32) < K;
    if (nx) LOADT(k0 + 32);
    bfrag ah[2], al[2], bh[4], bl[4];
#pragma unroll
    for (int t = 0; t < 2; ++t) {
      int ra = (wm + t * 16 + fr) * AP + fq * 8;
      ah[t] = *(const bfrag*)&sAh[ra];
      al[t] = *(const bfrag*)&sAl[ra];
    }
#pragma unroll
    for (int t = 0; t < 4; ++t) {
      int rb = (wn + t * 16 + fr) * AP + fq * 8;
      bh[t] = *(const bfrag*)&sBh[rb];
      bl[t] = *(const bfrag*)&sBl[rb];
    }
#pragma unroll
    for (int mt = 0; mt < 2; ++mt)
#pragma unroll
      for (int nt = 0; nt < 4; ++nt) {
        acc[mt][nt] = __builtin_amdgcn_mfma_f32_16x16x32_bf16(ah[mt], bh[nt], acc[mt][nt], 0, 0, 0);
        acc[mt][nt] = __builtin_amdgcn_mfma_f32_16x16x32_bf16(ah[mt], bl[nt], acc[mt][nt], 0, 0, 0);
        acc[mt][nt] = __builtin_amdgcn_mfma_f32_16x16x32_bf16(al[mt], bh[nt], acc[mt][nt], 0, 0, 0);
      }
    __syncthreads();
    if (nx) STORET();
  }
#undef LOADT
#undef STORET
  if (mode == 3) {
    float bv0 = bias[c0 + wn + fr];
    float bv1 = bias[c0 + wn + 16 + fr];
    float bv2 = bias[c0 + wn + 32 + fr];
    float bv3 = bias[c0 + wn + 48 + fr];
    int u = (c0 >> 2) + (wn >> 2) + fr;
#pragma unroll
    for (int mt = 0; mt < 2; ++mt)
#pragma unroll
      for (int rg = 0; rg < 4; ++rg) {
        int m = r0 + wm + mt * 16 + fq * 4 + rg;
        float gi = acc[mt][0][rg] + bv0;
        float gf = acc[mt][1][rg] + bv1;
        float gg = acc[mt][2][rg] + bv2;
        float go = acc[mt][3][rg] + bv3;
        float si = 1.f / (1.f + __expf(-gi));
        float sf = 1.f / (1.f + __expf(-gf));
        float so = 1.f / (1.f + __expf(-go));
        float tg = tanhf(gg);
        size_t ci = (size_t)m * 256 + u;
        float cn = sf * cst[ci] + si * tg;
        cst[ci] = cn;
        float hn = so * tanhf(cn);
        ushort hi = f2bf(hn);
        hoh[ci] = hi;
        hol[ci] = f2bf(hn - bf2f(hi));
      }
    return;
  }
#pragma unroll
  for (int mt = 0; mt < 2; ++mt)
#pragma unroll
    for (int nt = 0; nt < 4; ++nt) {
      int n = c0 + wn + nt * 16 + fr;
      float bv = bias[n];
#pragma unroll
      for (int rg = 0; rg < 4; ++rg) {
        int m = r0 + wm + mt * 16 + fq * 4 + rg;
        float v = acc[mt][nt][rg] + bv;
        if (mode == 2) {
          v = fmaxf(v, 0.f);
          ushort hi = f2bf(v);
          Chi[(size_t)m * N + n] = hi;
          Clo[(size_t)m * N + n] = f2bf(v - bf2f(hi));
        } else {
          Cf[(size_t)m * N + n] = v;
        }
      }
    }
}

extern "C" void kernel_launch(void* const* d_in, const int* in_sizes, int n_in,
                              void* d_out, int out_size, void* d_ws, size_t ws_size,
                              hipStream_t stream) {
  const float* emb   = (const float*)d_in[0];
  const int*   idx32 = (const int*)d_in[1];
  const float* W_ih  = (const float*)d_in[2];
  const float* W_hh  = (const float*)d_in[3];
  const float* b_ih  = (const float*)d_in[4];
  const float* b_hh  = (const float*)d_in[5];
  const float* W1    = (const float*)d_in[6];
  const float* b1    = (const float*)d_in[7];
  const float* W2    = (const float*)d_in[8];
  const float* b2    = (const float*)d_in[9];
  float* out = (float*)d_out;
  int N = in_sizes[1];

  char* ws = (char*)d_ws;
  size_t o = 0;
  auto alloc = [&](size_t bytes) { void* p = ws + o; o = (o + bytes + 255) & ~(size_t)255; return p; };
  int*    flag  = (int*)alloc(4);
  int*    starts= (int*)alloc(((size_t)NG + 1) * 4);
  float*  bcat  = (float*)alloc(1024 * 4);
  ushort* Wch   = (ushort*)alloc((size_t)1024 * 512 * 2);
  ushort* Wcl   = (ushort*)alloc((size_t)1024 * 512 * 2);
  ushort* W1h   = (ushort*)alloc((size_t)256 * 512 * 2);
  ushort* W1l   = (ushort*)alloc((size_t)256 * 512 * 2);
  ushort* W2h   = (ushort*)alloc((size_t)256 * 256 * 2);
  ushort* W2l   = (ushort*)alloc((size_t)256 * 256 * 2);
  float*  c     = (float*)alloc((size_t)NG * 256 * 4);
  ushort* hbh0  = (ushort*)alloc((size_t)NG * 256 * 2);
  ushort* hbl0  = (ushort*)alloc((size_t)NG * 256 * 2);
  ushort* hbh1  = (ushort*)alloc((size_t)NG * 256 * 2);
  ushort* hbl1  = (ushort*)alloc((size_t)NG * 256 * 2);
  ushort* rbh   = (ushort*)alloc((size_t)NG * 256 * 2);
  ushort* rbl   = (ushort*)alloc((size_t)NG * 256 * 2);
  ushort* hdnh  = (ushort*)alloc((size_t)NG * 256 * 2);
  ushort* hdnl  = (ushort*)alloc((size_t)NG * 256 * 2);
  ushort* e16   = (ushort*)alloc((size_t)N * 256 * 2);   // fp16 shadow of emb

  detect_kernel<<<1, 256, 0, stream>>>(idx32, flag);
  bounds_kernel<<<(N + 255) / 256, 256, 0, stream>>>(idx32, flag, starts, N);
  wprep_kernel<<<(524288 + 131072 + 65536) / 256, 256, 0, stream>>>(
      W_ih, W_hh, b_ih, b_hh, W1, W2, Wch, Wcl, W1h, W1l, W2h, W2l, bcat);
  attn0_kernel<<<NG, 256, 0, stream>>>(emb, starts, e16, c, hbh0, hbl0, rbh, rbl);

  for (int s = 0; s < 6; ++s) {
    const ushort* hch = (s & 1) ? hbh1 : hbh0;
    const ushort* hcl = (s & 1) ? hbl1 : hbl0;
    ushort* hnh = (s & 1) ? hbh0 : hbh1;
    ushort* hnl = (s & 1) ? hbl0 : hbl1;
    gemm_mfma<<<dim3(1024 / 128, 4096 / 64), 256, 0, stream>>>(
        hch, hcl, rbh, rbl, Wch, Wcl, bcat,
        (float*)nullptr, (ushort*)nullptr, (ushort*)nullptr,
        c, hnh, hnl, 1024, 512, 3);
    if (s < 5)
      attn_kernel<<<NG, 256, 0, stream>>>(e16, starts, hnh, hnl, rbh, rbl);
  }
  // after s=5: h6 lives in hb0, r5 in rb
  gemm_mfma<<<dim3(256 / 128, 4096 / 64), 256, 0, stream>>>(
      hbh0, hbl0, rbh, rbl, W1h, W1l, b1,
      (float*)nullptr, hdnh, hdnl,
      (float*)nullptr, (ushort*)nullptr, (ushort*)nullptr, 256, 512, 2);
  gemm_mfma<<<dim3(256 / 128, 4096 / 64), 256, 0, stream>>>(
      hdnh, hdnl, hdnh, hdnl, W2h, W2l, b2,
      out, (ushort*)nullptr, (ushort*)nullptr,
      (float*)nullptr, (ushort*)nullptr, (ushort*)nullptr, 256, 256, 0);
}